// Round 2
// baseline (884.063 us; speedup 1.0000x reference)
//
#include <hip/hip_runtime.h>
#include <hip/hip_bf16.h>

#define LN_EPS 1e-5f

// ---------------- CSR build ----------------

__global__ __launch_bounds__(256) void hist_kernel(
    const int* __restrict__ ei, int* __restrict__ deg, int E)
{
    int e = blockIdx.x * 256 + threadIdx.x;
    if (e < E) atomicAdd(&deg[ei[E + e]], 1);
}

// tile = 2048 elements per block (256 threads x 8). Writes per-tile exclusive
// prefix into rowstart[i], tile total into tilesum[tile].
__global__ __launch_bounds__(256) void scan1_kernel(
    const int* __restrict__ deg, int* __restrict__ rowstart,
    int* __restrict__ tilesum, int n)
{
    __shared__ int wsum[4];
    int t = threadIdx.x;
    int base = blockIdx.x * 2048 + t * 8;
    int v[8]; int tsum = 0;
    #pragma unroll
    for (int i = 0; i < 8; ++i) { v[i] = (base + i < n) ? deg[base + i] : 0; tsum += v[i]; }
    int lane = t & 63, w = t >> 6;
    int sc = tsum;
    #pragma unroll
    for (int off = 1; off < 64; off <<= 1) {
        int y = __shfl_up(sc, off);
        if (lane >= off) sc += y;
    }
    if (lane == 63) wsum[w] = sc;
    __syncthreads();
    int woff = 0;
    for (int j = 0; j < w; ++j) woff += wsum[j];
    int run = woff + sc - tsum;           // exclusive prefix of this thread's chunk
    #pragma unroll
    for (int i = 0; i < 8; ++i) { if (base + i < n) rowstart[base + i] = run; run += v[i]; }
    if (t == 255) tilesum[blockIdx.x] = wsum[0] + wsum[1] + wsum[2] + wsum[3];
}

// exclusive scan of tile sums (T <= 64) — single thread, trivial work
__global__ void scan2_kernel(int* tilesum, int T)
{
    if (blockIdx.x == 0 && threadIdx.x == 0) {
        int run = 0;
        for (int i = 0; i < T; ++i) { int v = tilesum[i]; tilesum[i] = run; run += v; }
    }
}

__global__ __launch_bounds__(256) void scan3_kernel(
    int* __restrict__ rowstart, const int* __restrict__ tilesum, int n, int E)
{
    int i = blockIdx.x * 256 + threadIdx.x;
    if (i < n) rowstart[i] += tilesum[i >> 11];
    if (i == 0) rowstart[n] = E;
}

__global__ __launch_bounds__(256) void fill_kernel(
    const int* __restrict__ ei, const int* __restrict__ rowstart,
    int* __restrict__ cursor, int* __restrict__ esrc, int E)
{
    int e = blockIdx.x * 256 + threadIdx.x;
    if (e < E) {
        int dst = ei[E + e];
        int pos = rowstart[dst] + atomicAdd(&cursor[dst], 1);
        esrc[pos] = ei[e];
    }
}

// ---------------- fused gather + SAGE + LN + ELU ----------------
// Block = 512 (8 waves), 4 nodes per wave -> 32 nodes per block.
// Weights staged TRANSPOSED in LDS: sWlT[d][j] so lane j's read of column d is
// contiguous across lanes (2-way alias = free). Feature rows read back as
// uniform-address float4 broadcasts (free).
#define NPW 4

__global__ __launch_bounds__(512) void fused_kernel(
    const float* __restrict__ x,
    const int*   __restrict__ rowstart,
    const int*   __restrict__ esrc,
    const float* __restrict__ Wl,
    const float* __restrict__ Wr,
    const float* __restrict__ bias,
    const float* __restrict__ gamma,
    const float* __restrict__ beta,
    float* __restrict__ out,
    int N)
{
    __shared__ float sWlT[64][65];  // [d][j], +1 pad
    __shared__ float sWrT[64][65];
    __shared__ float sm[32][68];    // mean rows, stride 68 -> 16B-aligned float4
    __shared__ float sx[32][68];    // self rows

    int tid  = threadIdx.x;
    int lane = tid & 63;
    int w    = tid >> 6;            // 0..7

    // stage transposed weights (writes: lanes vary d -> bank (d+j)%32, 2-way free)
    for (int i = tid; i < 64 * 64; i += 512) {
        int j = i >> 6, d = i & 63;
        sWlT[d][j] = Wl[i];
        sWrT[d][j] = Wr[i];
    }
    __syncthreads();

    int nbase = blockIdx.x * 32 + w * NPW;
    int rows  = w * NPW;

    // Phase A: CSR gather (lane = feature d). Unroll 4 for memory-level parallelism.
    #pragma unroll
    for (int i = 0; i < NPW; ++i) {
        int node = nbase + i;
        if (node >= N) break;
        int s0 = rowstart[node], s1 = rowstart[node + 1];
        float macc = 0.0f;
        int e = s0;
        for (; e + 4 <= s1; e += 4) {
            int a0 = esrc[e], a1 = esrc[e + 1], a2 = esrc[e + 2], a3 = esrc[e + 3];
            float v0 = x[(size_t)a0 * 64 + lane];
            float v1 = x[(size_t)a1 * 64 + lane];
            float v2 = x[(size_t)a2 * 64 + lane];
            float v3 = x[(size_t)a3 * 64 + lane];
            macc += v0 + v1 + v2 + v3;
        }
        for (; e < s1; ++e) macc += x[(size_t)esrc[e] * 64 + lane];
        float inv = 1.0f / fmaxf((float)(s1 - s0), 1.0f);
        sm[rows + i][lane] = macc * inv;
        sx[rows + i][lane] = x[(size_t)node * 64 + lane];
    }
    // same-wave LDS write->read: compiler inserts lgkmcnt wait; no barrier needed

    // Phase B: dual matvec. lane = output channel j.
    float bj = bias[lane];
    float acc[NPW];
    #pragma unroll
    for (int n = 0; n < NPW; ++n) acc[n] = bj;

    #pragma unroll
    for (int c = 0; c < 16; ++c) {
        int d0 = c * 4;
        float wl0 = sWlT[d0 + 0][lane], wl1 = sWlT[d0 + 1][lane];
        float wl2 = sWlT[d0 + 2][lane], wl3 = sWlT[d0 + 3][lane];
        float wr0 = sWrT[d0 + 0][lane], wr1 = sWrT[d0 + 1][lane];
        float wr2 = sWrT[d0 + 2][lane], wr3 = sWrT[d0 + 3][lane];
        #pragma unroll
        for (int n = 0; n < NPW; ++n) {
            float4 mb = *(const float4*)&sm[rows + n][d0];
            float4 xb = *(const float4*)&sx[rows + n][d0];
            acc[n] += mb.x * wl0 + mb.y * wl1 + mb.z * wl2 + mb.w * wl3
                    + xb.x * wr0 + xb.y * wr1 + xb.z * wr2 + xb.w * wr3;
        }
    }

    // Phase C: LayerNorm over 64 lanes + ELU, per node
    float g  = gamma[lane];
    float bt = beta[lane];
    #pragma unroll
    for (int n = 0; n < NPW; ++n) {
        int node = nbase + n;
        if (node >= N) break;
        float h = acc[n];
        float s = h, s2 = h * h;
        #pragma unroll
        for (int off = 32; off >= 1; off >>= 1) {
            s  += __shfl_xor(s,  off);
            s2 += __shfl_xor(s2, off);
        }
        float mu  = s * (1.0f / 64.0f);
        float var = s2 * (1.0f / 64.0f) - mu * mu;
        float hn  = (h - mu) * rsqrtf(var + LN_EPS) * g + bt;
        out[(size_t)node * 64 + lane] = hn > 0.0f ? hn : expm1f(hn);
    }
}

extern "C" void kernel_launch(void* const* d_in, const int* in_sizes, int n_in,
                              void* d_out, int out_size, void* d_ws, size_t ws_size,
                              hipStream_t stream) {
    const float* x     = (const float*)d_in[0];
    const int*   ei    = (const int*)  d_in[1];
    const float* Wl    = (const float*)d_in[2];
    const float* Wr    = (const float*)d_in[3];
    const float* bias  = (const float*)d_in[4];
    const float* gamma = (const float*)d_in[5];
    const float* beta  = (const float*)d_in[6];

    int N = in_sizes[0] / 64;
    int E = in_sizes[1] / 2;

    int* deg      = (int*)d_ws;            // N
    int* cursor   = deg + N;               // N   (contiguous with deg -> one memset)
    int* rowstart = cursor + N;            // N+1
    int* tilesum  = rowstart + (N + 1);    // <=64
    int* esrc     = tilesum + 64;          // E

    hipMemsetAsync(deg, 0, (size_t)2 * N * sizeof(int), stream);

    int eblocks = (E + 255) / 256;
    hist_kernel<<<eblocks, 256, 0, stream>>>(ei, deg, E);

    int T = (N + 2047) / 2048;             // 49 for N=100k (fits tilesum[64])
    scan1_kernel<<<T, 256, 0, stream>>>(deg, rowstart, tilesum, N);
    scan2_kernel<<<1, 64, 0, stream>>>(tilesum, T);
    scan3_kernel<<<(N + 255) / 256, 256, 0, stream>>>(rowstart, tilesum, N, E);

    fill_kernel<<<eblocks, 256, 0, stream>>>(ei, rowstart, cursor, esrc, E);

    int nblocks = (N + 31) / 32;
    fused_kernel<<<nblocks, 512, 0, stream>>>(x, rowstart, esrc, Wl, Wr,
                                              bias, gamma, beta, (float*)d_out, N);
}